// Round 3
// baseline (72.738 us; speedup 1.0000x reference)
//
#include <hip/hip_runtime.h>
#include <math.h>

#define T 2048
#define D 3
#define P 3
#define NK 11              // 2*KMAX+1
#define SUM_K2 110.0f      // 2*(1+4+9+16+25)
#define TWO_PI_F 6.28318530717958647692f
#define INV_TWO_PI_F 0.15915494309189533577f
#define PI_F 3.14159265358979323846f

// Torus logmap: wrap to [-pi, pi]. Reference is floor-mod -> [-pi, pi);
// differs only at the exact +/-pi boundary (measure-zero), threshold ~1.7e9.
// 2 VALU ops: v_rndne_f32 + v_fmac_f32 — vs ocml fmodf's branchy path.
__device__ __forceinline__ float wrap_pi(float x) {
    float k = rintf(x * INV_TWO_PI_F);
    return fmaf(-k, TWO_PI_F, x);
}

__global__ __launch_bounds__(256) void arp_kernel(
    const float* __restrict__ g,
    const float* __restrict__ ar_phi,   // (D,P)
    const float* __restrict__ ar_eta,   // (D,)
    const float* __restrict__ ar_c,     // (D,)
    float* __restrict__ out,            // (n_mc,)
    int n_samples)
{
    __shared__ float sg[T * D];          // 24 KiB: raw angles, one series/block
    __shared__ float wave_sums[4];

    const int series = blockIdx.x;            // mc * n_samples + sample
    const int mc     = series / n_samples;
    const int tid    = threadIdx.x;

    // Phase 1: coalesced float4 staging of the whole series into LDS.
    {
        const float4* src = (const float4*)(g + (size_t)series * (T * D));
        float4* dst = (float4*)sg;
        const int nvec = (T * D) / 4;         // 1536; 6 iters/thread
        for (int i = tid; i < nvec; i += 256) dst[i] = src[i];
    }

    // Params + analytic winding constant BEFORE the barrier — overlaps the
    // LDS-staging wait (scalar/L2-served, no LDS dependence).
    float ph[D][P], inv_s2[D], cc[D];
    float Cd_sum = 0.0f;
    #pragma unroll
    for (int d = 0; d < D; ++d) {
        float s = fabsf(ar_eta[d]);           // scale = sqrt(eta^2)
        inv_s2[d] = 1.0f / (s * s);
        cc[d] = ar_c[d];
        #pragma unroll
        for (int j = 0; j < P; ++j) ph[d][j] = ar_phi[d * P + j];
        // Sum over 11 windings of the non-quadratic parts:
        //   -0.5/s^2 * 4pi^2 * SUM_K2  - NK*log(s) - (NK/2)*log(2pi)
        Cd_sum += -0.5f * inv_s2[d] * (4.0f * PI_F * PI_F * SUM_K2)
                  - (float)NK * logf(s)
                  - 0.5f * (float)NK * logf(TWO_PI_F);
    }
    __syncthreads();

    // Phase 2 (merged): per t read 15 contiguous floats g[t..t+4][0..2]
    // (lane stride 12 B -> bank stride 3, coprime with 32 -> free 2-way
    // aliasing only; contiguous thread-local reads fuse to ds_read_b128),
    // wrap inline (2 ops each), accumulate quadratic term.
    const int Tp = T - 1 - P;                 // 2044
    float acc = 0.0f;
    for (int t = tid; t < Tp; t += 256) {
        float a[15];                          // g[t+0..t+4][d=0..2]
        #pragma unroll
        for (int m = 0; m < 15; ++m) a[m] = sg[t * D + m];
        float dx[12];                         // dx[j][d] = wrap(g[t+j+1][d]-g[t+j][d])
        #pragma unroll
        for (int m = 0; m < 12; ++m) dx[m] = wrap_pi(a[m + 3] - a[m]);
        #pragma unroll
        for (int d = 0; d < D; ++d) {
            float dy = dx[9 + d] - (ph[d][0] * dx[6 + d]
                                  + ph[d][1] * dx[3 + d]
                                  + ph[d][2] * dx[d]);
            float z = dy - cc[d];
            acc += -0.5f * (float)NK * z * z * inv_s2[d];   // -5.5 z^2 / s^2
        }
    }

    // Wave shuffle reduction, then cross-wave via LDS.
    #pragma unroll
    for (int off = 32; off > 0; off >>= 1) acc += __shfl_down(acc, off, 64);
    const int wave = tid >> 6, lane = tid & 63;
    if (lane == 0) wave_sums[wave] = acc;
    __syncthreads();
    if (tid == 0) {
        float block_sum = wave_sums[0] + wave_sums[1] + wave_sums[2] + wave_sums[3];
        block_sum += (float)Tp * Cd_sum;      // analytic constant, once/series
        atomicAdd(&out[mc], block_sum);
    }
}

extern "C" void kernel_launch(void* const* d_in, const int* in_sizes, int n_in,
                              void* d_out, int out_size, void* d_ws, size_t ws_size,
                              hipStream_t stream) {
    const float* g      = (const float*)d_in[0];
    const float* ar_phi = (const float*)d_in[1];
    const float* ar_eta = (const float*)d_in[2];
    const float* ar_c   = (const float*)d_in[3];
    float* out = (float*)d_out;

    const int n_series  = in_sizes[0] / (T * D);   // n_mc * n_samples = 512
    const int n_mc      = out_size;                // 32
    const int n_samples = n_series / n_mc;         // 16

    // d_out is poisoned (0xAA) before every timed launch — zero it ourselves.
    hipMemsetAsync(out, 0, (size_t)out_size * sizeof(float), stream);
    arp_kernel<<<n_series, 256, 0, stream>>>(g, ar_phi, ar_eta, ar_c, out, n_samples);
}